// Round 3
// baseline (133.419 us; speedup 1.0000x reference)
//
#include <hip/hip_runtime.h>

typedef __attribute__((ext_vector_type(4))) float  f32x4;
typedef __attribute__((ext_vector_type(8))) short  bf16x8;
typedef __attribute__((ext_vector_type(4))) unsigned int u32x4;

#define MFMA16(a,b,c) __builtin_amdgcn_mfma_f32_16x16x32_bf16(a,b,c,0,0,0)
#define SCL   0.360673760f   /* 0.25*log2(e) */
#define PBIAS 17.3123405f    /* fixed exp bias; normalized by sum in epilogue -> exact softmax */

static __device__ __forceinline__ unsigned short f2bf(float f){
  unsigned int u = __float_as_uint(f);
  u += 0x7fffu + ((u>>16)&1u);
  return (unsigned short)(u>>16);
}
static __device__ __forceinline__ unsigned int pk2(float a, float b){
  return (unsigned)f2bf(a) | (((unsigned)f2bf(b))<<16);
}

// ---------------------------------------------------------------------------
// prep: q,k = x @ w^T + b  (bf16 out), and xbT[b][d][s] = bf16(x) transposed
// grid 256 blocks x 256 thr; each block = 64 rows of flat [8*2048]
// ---------------------------------------------------------------------------
__global__ __launch_bounds__(256,2) void prep_kernel(
    const float* __restrict__ x,  const float* __restrict__ wq, const float* __restrict__ bq,
    const float* __restrict__ wk, const float* __restrict__ bk,
    unsigned short* __restrict__ qws, unsigned short* __restrict__ kws,
    unsigned short* __restrict__ xbT)
{
  __shared__ __align__(16) unsigned short wlds[32*1032];  // [32 e][1024 k] pad 8
  __shared__ __align__(16) unsigned short xlds[64*72];    // [64 s][64 k] pad 8
  const int t  = threadIdx.x;
  const int r0 = blockIdx.x<<6;
  const int b  = r0>>11;
  const int s0 = r0&2047;
  const int l = t&63, w = t>>6, g = l>>4, li = l&15;

  { // stage weights once (rows 0..15 = wq, 16..31 = wk)
    const int n = t>>3, part = t&7;
    const float* wsrc = (n<16) ? (wq + n*1024) : (wk + (n-16)*1024);
    #pragma unroll
    for(int cc=0; cc<16; ++cc){
      const int d = part*128 + cc*8;
      f32x4 f0 = *(const f32x4*)(wsrc + d);
      f32x4 f1 = *(const f32x4*)(wsrc + d + 4);
      u32x4 p;
      p[0]=pk2(f0[0],f0[1]); p[1]=pk2(f0[2],f0[3]);
      p[2]=pk2(f1[0],f1[1]); p[3]=pk2(f1[2],f1[3]);
      *(u32x4*)(&wlds[n*1032 + d]) = p;
    }
  }
  __syncthreads();

  f32x4 acc0 = {0.f,0.f,0.f,0.f};
  f32x4 acc1 = {0.f,0.f,0.f,0.f};
  const int srow = t>>2, dch = t&3;   // staging roles
  const int dd = t&63, sch = t>>6;    // transpose roles

  for(int it=0; it<16; ++it){
    { // stage x[64][64] -> bf16 LDS (coalesced f32x4 reads)
      const float* xp = x + (size_t)(r0+srow)*1024 + it*64 + dch*16;
      f32x4 a0 = *(const f32x4*)(xp);
      f32x4 a1 = *(const f32x4*)(xp+4);
      f32x4 a2 = *(const f32x4*)(xp+8);
      f32x4 a3 = *(const f32x4*)(xp+12);
      u32x4 p0, p1;
      p0[0]=pk2(a0[0],a0[1]); p0[1]=pk2(a0[2],a0[3]);
      p0[2]=pk2(a1[0],a1[1]); p0[3]=pk2(a1[2],a1[3]);
      p1[0]=pk2(a2[0],a2[1]); p1[1]=pk2(a2[2],a2[3]);
      p1[2]=pk2(a3[0],a3[1]); p1[3]=pk2(a3[2],a3[3]);
      *(u32x4*)(&xlds[srow*72 + dch*16])     = p0;
      *(u32x4*)(&xlds[srow*72 + dch*16 + 8]) = p1;
    }
    __syncthreads();
    #pragma unroll
    for(int ks=0; ks<2; ++ks){
      bf16x8 a  = *(const bf16x8*)(&xlds[(16*w+li)*72       + ks*32 + g*8]);
      bf16x8 b0 = *(const bf16x8*)(&wlds[ li*1032     + it*64 + ks*32 + g*8]);
      bf16x8 b1 = *(const bf16x8*)(&wlds[(16+li)*1032 + it*64 + ks*32 + g*8]);
      acc0 = MFMA16(a,b0,acc0);
      acc1 = MFMA16(a,b1,acc1);
    }
    { // transpose-write xbT[b][d][s]
      unsigned short v[16];
      #pragma unroll
      for(int jj=0; jj<16; ++jj) v[jj] = xlds[(sch*16 + jj)*72 + dd];
      u32x4 o0, o1;
      o0[0]=(unsigned)v[0]|((unsigned)v[1]<<16);   o0[1]=(unsigned)v[2]|((unsigned)v[3]<<16);
      o0[2]=(unsigned)v[4]|((unsigned)v[5]<<16);   o0[3]=(unsigned)v[6]|((unsigned)v[7]<<16);
      o1[0]=(unsigned)v[8]|((unsigned)v[9]<<16);   o1[1]=(unsigned)v[10]|((unsigned)v[11]<<16);
      o1[2]=(unsigned)v[12]|((unsigned)v[13]<<16); o1[3]=(unsigned)v[14]|((unsigned)v[15]<<16);
      unsigned short* dst = xbT + (size_t)(b*1024 + it*64 + dd)*2048 + s0 + sch*16;
      *(u32x4*)(dst)   = o0;
      *(u32x4*)(dst+8) = o1;
    }
    __syncthreads();
  }
  #pragma unroll
  for(int reg=0; reg<4; ++reg){
    const int sr = r0 + 16*w + 4*g + reg;
    qws[(size_t)sr*16 + li] = f2bf(acc0[reg] + bq[li]);
    kws[(size_t)sr*16 + li] = f2bf(acc1[reg] + bk[li]);
  }
}

// ---------------------------------------------------------------------------
// attn v3: block = (b, 64-q, 256-d quarter); 4 waves, each 64q x private 64d.
// Barrier-free: X tile LDS is wave-private (global_load_lds width16, dbuf),
// S in-register via permuted-K trick, counted vmcnt(6) pipeline.
// grid 1024 x 256 thr. LDS 32KB. 3 blocks/CU.
// ---------------------------------------------------------------------------
typedef const unsigned int GASU __attribute__((address_space(1)));
typedef unsigned int LASU __attribute__((address_space(3)));

__global__ __launch_bounds__(256,3) void attn_kernel(
    const unsigned short* __restrict__ qws, const unsigned short* __restrict__ kws,
    const unsigned short* __restrict__ xbT, float* __restrict__ out)
{
  __shared__ __align__(16) unsigned char smem[32768];  // 2 bufs x [256 d][32 kv] bf16
  const int t = threadIdx.x;
  const int l = t&63, w = t>>6, g = l>>4, li = l&15;
  const int bi = blockIdx.x;
  const int b = bi&7;                 // XCD batch affinity
  const int j = bi>>3;
  const int qb = 31-(j>>2), dq = j&3; // LPT: big q-blocks dispatched first
  const int q0 = qb<<6, d0 = dq<<8, nt = 2*qb + 2;

  // K-row permutation: C-row r of S-MFMA corresponds to kv = 8*(r>>2)+(r&3)
  const int kperm = ((li>>2)<<3) + (li&3);

  const bf16x8 zero8 = {0,0,0,0,0,0,0,0};
  bf16x8 qfr[4];
  #pragma unroll
  for(int qf=0;qf<4;++qf){
    qfr[qf] = zero8;
    if(g < 2) qfr[qf] = *(const bf16x8*)(qws + ((size_t)(b*2048 + q0 + 16*qf + li)<<4) + 8*g);
  }

  f32x4 acc[4][4];
  #pragma unroll
  for(int i=0;i<4;++i)
    #pragma unroll
    for(int jj=0;jj<4;++jj){ acc[i][jj][0]=0.f; acc[i][jj][1]=0.f; acc[i][jj][2]=0.f; acc[i][jj][3]=0.f; }
  float sp[4] = {0.f,0.f,0.f,0.f};

  // wave-private staging: wave w stages+reads rows [64w, 64w+64) only
  const unsigned short* xb = xbT + (size_t)(b*1024 + d0 + w*64)*2048;
  const int srow = l>>2, scol = (l&3)*8;

  auto stage = [&](int bufOff, int kv0_){
    const unsigned short* src = xb + (size_t)srow*2048 + kv0_ + scol;
    #pragma unroll
    for(int r=0;r<4;++r){
      __builtin_amdgcn_global_load_lds((GASU*)(src + (size_t)r*16*2048),
                                       (LASU*)(&smem[bufOff + w*4096 + r*1024]),
                                       16, 0, 0);
    }
  };

  bf16x8 k1 = zero8, k2 = zero8, k1n = zero8, k2n = zero8;
  // prologue: K(0) then stage(0) -> always 2 K-loads + 4 stage ops per step
  if(g < 2){
    const unsigned short* kp = kws + ((size_t)(b*2048 + kperm)<<4) + 8*g;
    k1 = *(const bf16x8*)(kp);
    k2 = *(const bf16x8*)(kp + 64);   // +4 rows * 16 shorts
  }
  stage(0, 0);

  int buf = 0;
  for(int tt=0; tt<nt; ++tt){
    const int kv0 = tt<<5;
    const bool pf = (tt+1 < nt);
    if(pf){
      if(g < 2){
        const unsigned short* kp = kws + ((size_t)(b*2048 + ((tt+1)<<5) + kperm)<<4) + 8*g;
        k1n = *(const bf16x8*)(kp);
        k2n = *(const bf16x8*)(kp + 64);
      }
      stage((buf^1)*16384, (tt+1)<<5);
    }
    // ---- S: S^T frags via permuted K; p in-register, PV-A slot order ----
    bf16x8 afr[4];
    const bool msk = (tt >= nt-2);
    #pragma unroll
    for(int qf=0; qf<4; ++qf){
      f32x4 z = {0.f,0.f,0.f,0.f};
      f32x4 s1 = MFMA16(k1, qfr[qf], z);   // rows kv 8g+0..3 (perm)
      f32x4 s2 = MFMA16(k2, qfr[qf], z);   // rows kv 8g+4..7
      float p[8];
      if(!msk){
        #pragma unroll
        for(int r4=0;r4<4;++r4){
          p[r4]   = exp2f(fmaf(s1[r4], SCL, -PBIAS));
          p[4+r4] = exp2f(fmaf(s2[r4], SCL, -PBIAS));
        }
      } else {
        const int qg = q0 + 16*qf + li;
        #pragma unroll
        for(int r4=0;r4<4;++r4){
          p[r4]   = (kv0 + 8*g + r4     <= qg) ? exp2f(fmaf(s1[r4], SCL, -PBIAS)) : 0.f;
          p[4+r4] = (kv0 + 8*g + 4 + r4 <= qg) ? exp2f(fmaf(s2[r4], SCL, -PBIAS)) : 0.f;
        }
      }
      sp[qf] += ((p[0]+p[1])+(p[2]+p[3])) + ((p[4]+p[5])+(p[6]+p[7]));
      unsigned int u0,u1,u2,u3;
      asm("v_cvt_pk_bf16_f32 %0, %1, %2" : "=v"(u0) : "v"(p[0]), "v"(p[1]));
      asm("v_cvt_pk_bf16_f32 %0, %1, %2" : "=v"(u1) : "v"(p[2]), "v"(p[3]));
      asm("v_cvt_pk_bf16_f32 %0, %1, %2" : "=v"(u2) : "v"(p[4]), "v"(p[5]));
      asm("v_cvt_pk_bf16_f32 %0, %1, %2" : "=v"(u3) : "v"(p[6]), "v"(p[7]));
      u32x4 av; av[0]=u0; av[1]=u1; av[2]=u2; av[3]=u3;
      afr[qf] = *(bf16x8*)&av;
    }
    // ---- wait current tile's stage (6 newer vmem ops in flight: 2K + 4 stage) ----
    if(pf){ asm volatile("s_waitcnt vmcnt(6)" ::: "memory"); }
    else  { asm volatile("s_waitcnt vmcnt(0)" ::: "memory"); }
    // ---- PV: acc[qf][df] += P @ X  (wave-private LDS, conflict-free b128) ----
    __builtin_amdgcn_s_setprio(1);
    const int xbase = buf*16384 + w*4096 + li*64 + g*16;
    #pragma unroll
    for(int df=0; df<4; ++df){
      bf16x8 bfr = *(const bf16x8*)(&smem[xbase + df*1024]);
      #pragma unroll
      for(int qf=0; qf<4; ++qf)
        acc[qf][df] = MFMA16(afr[qf], bfr, acc[qf][df]);
    }
    __builtin_amdgcn_s_setprio(0);
    buf ^= 1; k1 = k1n; k2 = k2n;
  }

  // ---- epilogue: normalize by row-sums (reduce over g-groups), store ----
  #pragma unroll
  for(int qf=0; qf<4; ++qf){
    float r_ = sp[qf];
    r_ += __shfl_xor(r_, 16);
    r_ += __shfl_xor(r_, 32);          // full sum for q = q0+16qf+li, in every lane
    #pragma unroll
    for(int reg=0; reg<4; ++reg){
      const float dv  = __shfl(r_, 4*g + reg, 16);  // sum for q-row 16qf+4g+reg
      const float inv = 1.0f/dv;
      float* op = out + (size_t)(b*2048 + q0 + 16*qf + 4*g + reg)*1024 + d0 + 64*w + li;
      #pragma unroll
      for(int df=0; df<4; ++df) op[df*16] = acc[qf][df][reg]*inv;
    }
  }
}

// ---------------------------------------------------------------------------
extern "C" void kernel_launch(void* const* d_in, const int* in_sizes, int n_in,
                              void* d_out, int out_size, void* d_ws, size_t ws_size,
                              hipStream_t stream) {
  (void)in_sizes; (void)n_in; (void)out_size; (void)ws_size;
  const float* x  = (const float*)d_in[0];
  const float* wq = (const float*)d_in[1];
  const float* bq = (const float*)d_in[2];
  const float* wk = (const float*)d_in[3];
  const float* bk = (const float*)d_in[4];
  float* out = (float*)d_out;
  char* ws = (char*)d_ws;
  unsigned short* qws = (unsigned short*)(ws);             // 512KB  [8*2048][16] bf16
  unsigned short* kws = (unsigned short*)(ws + (512<<10)); // 512KB
  unsigned short* xbT = (unsigned short*)(ws + (2<<20));   // 33.5MB [8][1024][2048] bf16
  hipLaunchKernelGGL(prep_kernel, dim3(256), dim3(256), 0, stream, x, wq, bq, wk, bk, qws, kws, xbT);
  hipLaunchKernelGGL(attn_kernel, dim3(1024), dim3(256), 0, stream, qws, kws, xbT, out);
}

// Round 4
// 112.351 us; speedup vs baseline: 1.1875x; 1.1875x over previous
//
#include <hip/hip_runtime.h>

typedef __attribute__((ext_vector_type(4))) float  f32x4;
typedef __attribute__((ext_vector_type(8))) short  bf16x8;
typedef __attribute__((ext_vector_type(4))) unsigned int u32x4;

#define MFMA16(a,b,c) __builtin_amdgcn_mfma_f32_16x16x32_bf16(a,b,c,0,0,0)
#define SCL   0.360673760f   /* 0.25*log2(e) */
#define PBIAS 17.3123405f    /* fixed exp bias; epilogue sum-normalize -> exact softmax */

static __device__ __forceinline__ unsigned short f2bf(float f){
  unsigned int u = __float_as_uint(f);
  u += 0x7fffu + ((u>>16)&1u);
  return (unsigned short)(u>>16);
}
static __device__ __forceinline__ unsigned int pk2(float a, float b){
  return (unsigned)f2bf(a) | (((unsigned)f2bf(b))<<16);
}

// ---------------------------------------------------------------------------
// prep: q,k = x @ w^T + b  (bf16 out), and xbT[b][d][s] = bf16(x) transposed
// ---------------------------------------------------------------------------
__global__ __launch_bounds__(256,2) void prep_kernel(
    const float* __restrict__ x,  const float* __restrict__ wq, const float* __restrict__ bq,
    const float* __restrict__ wk, const float* __restrict__ bk,
    unsigned short* __restrict__ qws, unsigned short* __restrict__ kws,
    unsigned short* __restrict__ xbT)
{
  __shared__ __align__(16) unsigned short wlds[32*1032];
  __shared__ __align__(16) unsigned short xlds[64*72];
  const int t  = threadIdx.x;
  const int r0 = blockIdx.x<<6;
  const int b  = r0>>11;
  const int s0 = r0&2047;
  const int l = t&63, w = t>>6, g = l>>4, li = l&15;

  { const int n = t>>3, part = t&7;
    const float* wsrc = (n<16) ? (wq + n*1024) : (wk + (n-16)*1024);
    #pragma unroll
    for(int cc=0; cc<16; ++cc){
      const int d = part*128 + cc*8;
      f32x4 f0 = *(const f32x4*)(wsrc + d);
      f32x4 f1 = *(const f32x4*)(wsrc + d + 4);
      u32x4 p;
      p[0]=pk2(f0[0],f0[1]); p[1]=pk2(f0[2],f0[3]);
      p[2]=pk2(f1[0],f1[1]); p[3]=pk2(f1[2],f1[3]);
      *(u32x4*)(&wlds[n*1032 + d]) = p;
    }
  }
  __syncthreads();

  f32x4 acc0 = {0.f,0.f,0.f,0.f};
  f32x4 acc1 = {0.f,0.f,0.f,0.f};
  const int srow = t>>2, dch = t&3;
  const int dd = t&63, sch = t>>6;

  for(int it=0; it<16; ++it){
    { const float* xp = x + (size_t)(r0+srow)*1024 + it*64 + dch*16;
      f32x4 a0 = *(const f32x4*)(xp);
      f32x4 a1 = *(const f32x4*)(xp+4);
      f32x4 a2 = *(const f32x4*)(xp+8);
      f32x4 a3 = *(const f32x4*)(xp+12);
      u32x4 p0, p1;
      p0[0]=pk2(a0[0],a0[1]); p0[1]=pk2(a0[2],a0[3]);
      p0[2]=pk2(a1[0],a1[1]); p0[3]=pk2(a1[2],a1[3]);
      p1[0]=pk2(a2[0],a2[1]); p1[1]=pk2(a2[2],a2[3]);
      p1[2]=pk2(a3[0],a3[1]); p1[3]=pk2(a3[2],a3[3]);
      *(u32x4*)(&xlds[srow*72 + dch*16])     = p0;
      *(u32x4*)(&xlds[srow*72 + dch*16 + 8]) = p1;
    }
    __syncthreads();
    #pragma unroll
    for(int ks=0; ks<2; ++ks){
      bf16x8 a  = *(const bf16x8*)(&xlds[(16*w+li)*72       + ks*32 + g*8]);
      bf16x8 b0 = *(const bf16x8*)(&wlds[ li*1032     + it*64 + ks*32 + g*8]);
      bf16x8 b1 = *(const bf16x8*)(&wlds[(16+li)*1032 + it*64 + ks*32 + g*8]);
      acc0 = MFMA16(a,b0,acc0);
      acc1 = MFMA16(a,b1,acc1);
    }
    { unsigned short v[16];
      #pragma unroll
      for(int jj=0; jj<16; ++jj) v[jj] = xlds[(sch*16 + jj)*72 + dd];
      u32x4 o0, o1;
      o0[0]=(unsigned)v[0]|((unsigned)v[1]<<16);   o0[1]=(unsigned)v[2]|((unsigned)v[3]<<16);
      o0[2]=(unsigned)v[4]|((unsigned)v[5]<<16);   o0[3]=(unsigned)v[6]|((unsigned)v[7]<<16);
      o1[0]=(unsigned)v[8]|((unsigned)v[9]<<16);   o1[1]=(unsigned)v[10]|((unsigned)v[11]<<16);
      o1[2]=(unsigned)v[12]|((unsigned)v[13]<<16); o1[3]=(unsigned)v[14]|((unsigned)v[15]<<16);
      unsigned short* dst = xbT + (size_t)(b*1024 + it*64 + dd)*2048 + s0 + sch*16;
      *(u32x4*)(dst)   = o0;
      *(u32x4*)(dst+8) = o1;
    }
    __syncthreads();
  }
  #pragma unroll
  for(int reg=0; reg<4; ++reg){
    const int sr = r0 + 16*w + 4*g + reg;
    qws[(size_t)sr*16 + li] = f2bf(acc0[reg] + bq[li]);
    kws[(size_t)sr*16 + li] = f2bf(acc1[reg] + bk[li]);
  }
}

// ---------------------------------------------------------------------------
// attn v4: block = (b, 64-q, 256-d quarter); 4 waves. Wave w computes S only
// for its own 16-q slice (qf=w), P-fragments shared via 4KB LDS. X tile
// wave-private dbuf via global_load_lds (kv-slot XOR-swizzled both sides).
// 2 syncthreads/tile; stage(tt+1) issued post-bar1 so latency hides under PV.
// grid 1024 x 256 thr; complement-balanced qb assignment per CU slot.
// ---------------------------------------------------------------------------
typedef const unsigned int GASU __attribute__((address_space(1)));
typedef unsigned int LASU __attribute__((address_space(3)));

#define POFF 32768

__global__ __launch_bounds__(256,3) void attn_kernel(
    const unsigned short* __restrict__ qws, const unsigned short* __restrict__ kws,
    const unsigned short* __restrict__ xbT, float* __restrict__ out)
{
  __shared__ __align__(16) unsigned char smem[32768 + 4096];  // X dbuf + P
  __shared__ float psL[64];
  const int t = threadIdx.x;
  const int l = t&63, w = t>>6, g = l>>4, li = l&15;
  const int bi = blockIdx.x;
  const int b = bi&7;                 // XCD batch affinity
  const int j = bi>>3;
  const int rr = j>>5, c = j&31;
  int qb;
  if(rr==0)      qb = 31-c;
  else if(rr==1) qb = c;
  else if(rr==2) qb = (c+8)&31;
  else           qb = 31-((c+8)&31);  // per-CU-slot qb sums ~62 -> balanced
  const int dq = rr;
  const int q0 = qb<<6, d0 = dq<<8, nt = 2*qb + 2;

  // K-row permutation: C-row r of S-MFMA corresponds to kv = 8*(r>>2)+(r&3)
  const int kperm = ((li>>2)<<3) + (li&3);

  const bf16x8 zero8 = {0,0,0,0,0,0,0,0};
  bf16x8 qfr = zero8;                 // own qf = w only
  if(g < 2) qfr = *(const bf16x8*)(qws + ((size_t)(b*2048 + q0 + 16*w + li)<<4) + 8*g);
  const int qg = q0 + 16*w + li;      // q row this lane's S column corresponds to

  f32x4 acc[4][4];
  #pragma unroll
  for(int i=0;i<4;++i)
    #pragma unroll
    for(int jj=0;jj<4;++jj){ acc[i][jj][0]=0.f; acc[i][jj][1]=0.f; acc[i][jj][2]=0.f; acc[i][jj][3]=0.f; }
  float sp = 0.f;

  // wave-private staging: wave w covers d rows [d0+64w, d0+64w+64)
  const unsigned short* xb = xbT + (size_t)(b*1024 + d0 + w*64)*2048;
  const int srow = l>>2;
  const int scol = 8*((l&3) ^ ((l>>3)&3));   // kv-slot XOR pre-swizzle (write side)
  const int bswz = 16*(g ^ ((li>>1)&3));     // matching read-side swizzle

  auto stage = [&](int bufOff, int kv0_){
    const unsigned short* src = xb + (size_t)srow*2048 + kv0_ + scol;
    #pragma unroll
    for(int r=0;r<4;++r){
      __builtin_amdgcn_global_load_lds((GASU*)(src + (size_t)r*16*2048),
                                       (LASU*)(&smem[bufOff + w*4096 + r*1024]),
                                       16, 0, 0);
    }
  };

  bf16x8 k1 = zero8, k2 = zero8, k1n = zero8, k2n = zero8;
  if(g < 2){
    const unsigned short* kp = kws + ((size_t)(b*2048 + kperm)<<4) + 8*g;
    k1 = *(const bf16x8*)(kp);
    k2 = *(const bf16x8*)(kp + 64);
  }
  stage(0, 0);

  int buf = 0;
  for(int tt=0; tt<nt; ++tt){
    const int kv0 = tt<<5;
    const bool pf = (tt+1 < nt);
    // ---- S: own 16q x 32kv slice only ----
    f32x4 z = {0.f,0.f,0.f,0.f};
    f32x4 s1 = MFMA16(k1, qfr, z);   // kv 8g+0..3 (perm rows)
    f32x4 s2 = MFMA16(k2, qfr, z);   // kv 8g+4..7
    float p[8];
    if(tt < nt-2){
      #pragma unroll
      for(int r4=0;r4<4;++r4){
        p[r4]   = exp2f(fmaf(s1[r4], SCL, -PBIAS));
        p[4+r4] = exp2f(fmaf(s2[r4], SCL, -PBIAS));
      }
    } else {
      #pragma unroll
      for(int r4=0;r4<4;++r4){
        p[r4]   = (kv0 + 8*g + r4     <= qg) ? exp2f(fmaf(s1[r4], SCL, -PBIAS)) : 0.f;
        p[4+r4] = (kv0 + 8*g + 4 + r4 <= qg) ? exp2f(fmaf(s2[r4], SCL, -PBIAS)) : 0.f;
      }
    }
    sp += ((p[0]+p[1])+(p[2]+p[3])) + ((p[4]+p[5])+(p[6]+p[7]));
    { unsigned int u0,u1,u2,u3;
      asm("v_cvt_pk_bf16_f32 %0, %1, %2" : "=v"(u0) : "v"(p[0]), "v"(p[1]));
      asm("v_cvt_pk_bf16_f32 %0, %1, %2" : "=v"(u1) : "v"(p[2]), "v"(p[3]));
      asm("v_cvt_pk_bf16_f32 %0, %1, %2" : "=v"(u2) : "v"(p[4]), "v"(p[5]));
      asm("v_cvt_pk_bf16_f32 %0, %1, %2" : "=v"(u3) : "v"(p[6]), "v"(p[7]));
      u32x4 av; av[0]=u0; av[1]=u1; av[2]=u2; av[3]=u3;
      *(u32x4*)(&smem[POFF + w*1024 + l*16]) = av;   // share own A-frag
    }
    __syncthreads();   // bar1: P visible; also drains stage(tt) (vmcnt 0)

    if(pf){ // prefetch next tile: latency hides under PV below
      if(g < 2){
        const unsigned short* kp = kws + ((size_t)(b*2048 + ((tt+1)<<5) + kperm)<<4) + 8*g;
        k1n = *(const bf16x8*)(kp);
        k2n = *(const bf16x8*)(kp + 64);
      }
      stage((buf^1)*16384, (tt+1)<<5);
    }

    // ---- PV: acc[qf][df] += P @ X ----
    __builtin_amdgcn_s_setprio(1);
    bf16x8 afr0 = *(const bf16x8*)(&smem[POFF +          l*16]);
    bf16x8 afr1 = *(const bf16x8*)(&smem[POFF + 1024 + l*16]);
    bf16x8 afr2 = *(const bf16x8*)(&smem[POFF + 2048 + l*16]);
    bf16x8 afr3 = *(const bf16x8*)(&smem[POFF + 3072 + l*16]);
    const int xbase = buf*16384 + w*4096 + li*64 + bswz;
    #pragma unroll
    for(int df=0; df<4; ++df){
      bf16x8 bfr = *(const bf16x8*)(&smem[xbase + df*1024]);
      acc[0][df] = MFMA16(afr0, bfr, acc[0][df]);
      acc[1][df] = MFMA16(afr1, bfr, acc[1][df]);
      acc[2][df] = MFMA16(afr2, bfr, acc[2][df]);
      acc[3][df] = MFMA16(afr3, bfr, acc[3][df]);
    }
    __builtin_amdgcn_s_setprio(0);
    __syncthreads();   // bar2: P reads done -> next tile may overwrite
    buf ^= 1; k1 = k1n; k2 = k2n;
  }

  // ---- epilogue: share row sums, normalize, store ----
  float r_ = sp;
  r_ += __shfl_xor(r_, 16);
  r_ += __shfl_xor(r_, 32);
  if(l < 16) psL[16*w + l] = r_;
  __syncthreads();
  #pragma unroll
  for(int qf=0; qf<4; ++qf){
    const f32x4 pv = *(const f32x4*)(&psL[16*qf + 4*g]);
    #pragma unroll
    for(int reg=0; reg<4; ++reg){
      const float inv = 1.0f/pv[reg];
      float* op = out + (size_t)(b*2048 + q0 + 16*qf + 4*g + reg)*1024 + d0 + 64*w + li;
      #pragma unroll
      for(int df=0; df<4; ++df) op[df*16] = acc[qf][df][reg]*inv;
    }
  }
}

// ---------------------------------------------------------------------------
extern "C" void kernel_launch(void* const* d_in, const int* in_sizes, int n_in,
                              void* d_out, int out_size, void* d_ws, size_t ws_size,
                              hipStream_t stream) {
  (void)in_sizes; (void)n_in; (void)out_size; (void)ws_size;
  const float* x  = (const float*)d_in[0];
  const float* wq = (const float*)d_in[1];
  const float* bq = (const float*)d_in[2];
  const float* wk = (const float*)d_in[3];
  const float* bk = (const float*)d_in[4];
  float* out = (float*)d_out;
  char* ws = (char*)d_ws;
  unsigned short* qws = (unsigned short*)(ws);             // 512KB  [8*2048][16] bf16
  unsigned short* kws = (unsigned short*)(ws + (512<<10)); // 512KB
  unsigned short* xbT = (unsigned short*)(ws + (2<<20));   // 33.5MB [8][1024][2048] bf16
  hipLaunchKernelGGL(prep_kernel, dim3(256), dim3(256), 0, stream, x, wq, bq, wk, bk, qws, kws, xbT);
  hipLaunchKernelGGL(attn_kernel, dim3(1024), dim3(256), 0, stream, qws, kws, xbT, out);
}